// Round 2
// baseline (806.912 us; speedup 1.0000x reference)
//
#include <hip/hip_runtime.h>
#include <hip/hip_bf16.h>
#include <math.h>

#define MBLK   64
#define WCOLS  544
#define ROWB   (WCOLS*2)      // 1088 bytes per LDS row
#define LDSB   (MBLK*ROWB)    // 69632 bytes

// packed bf16 weight offsets (ushort elements) inside d_ws
#define OFF_W1  0
#define OFF_W2  16384                    // 512*32
#define OFF_WS1 (16384+262144)           // 278528
#define OFF_WS2 (278528+278528)          // 557056
#define OFF_WO  (557056+262144)          // 819200
#define NPACK   (819200+1024)            // 820224

typedef __attribute__((ext_vector_type(8))) short bf16x8;
typedef __attribute__((ext_vector_type(4))) float f32x4;

struct ResArr { int r[10]; };

__device__ __forceinline__ unsigned short f2bf(float f) {
    unsigned u = __float_as_uint(f);
    u += 0x7FFFu + ((u >> 16) & 1u);       // RNE
    return (unsigned short)(u >> 16);
}
__device__ __forceinline__ float bf2f(unsigned short h) {
    return __uint_as_float(((unsigned)h) << 16);
}

__global__ void pack_weights(const float* __restrict__ w1, const float* __restrict__ w2,
                             const float* __restrict__ ws1, const float* __restrict__ ws2,
                             const float* __restrict__ wo, unsigned short* __restrict__ out)
{
    int i = blockIdx.x * 256 + threadIdx.x;
    if (i >= NPACK) return;
    float v;
    if (i < OFF_W2)       { int n = i >> 5,  k = i & 31;  v = (k < 22)  ? w1[n*22 + k]  : 0.f; }
    else if (i < OFF_WS1) { int j = i - OFF_W2;  int n = j >> 9, k = j & 511; v = w2[n*512 + k]; }
    else if (i < OFF_WS2) { int j = i - OFF_WS1; int n = j / 544, k = j - n*544; v = (k < 534) ? ws1[n*534 + k] : 0.f; }
    else if (i < OFF_WO)  { int j = i - OFF_WS2; int n = j >> 9, k = j & 511; v = ws2[n*512 + k]; }
    else                  { int j = i - OFF_WO;  v = wo[j]; }
    out[i] = f2bf(v);
}

// one MLP layer: act[64 x K] (LDS, bf16, swizzled) @ W^T -> sin -> act[64 x 512] in-place
template<int KSTEPS, int KPAD>
__device__ __forceinline__ void mlp_layer(char* sm, const unsigned short* __restrict__ Wp,
                                          const float* __restrict__ bias,
                                          int acolByte, int wid, int lane)
{
    const int n0 = wid * 64;
    const int lm = lane & 15;
    const int lk = lane >> 4;               // 0..3
    const int xm = (lm & 7) << 4;           // row-swizzle mask for A reads (row low bits = lm low bits)

    f32x4 acc[4][4];
    #pragma unroll
    for (int i = 0; i < 4; ++i)
        #pragma unroll
        for (int j = 0; j < 4; ++j) { f32x4 z = {0.f,0.f,0.f,0.f}; acc[i][j] = z; }

    const unsigned short* wb = Wp + (unsigned)(n0 + lm) * KPAD + lk * 8;

    #pragma unroll 2
    for (int ks = 0; ks < KSTEPS; ++ks) {
        const int kb = acolByte + ks * 64 + lk * 16;
        bf16x8 a[4], b[4];
        #pragma unroll
        for (int mf = 0; mf < 4; ++mf)
            a[mf] = *(const bf16x8*)(sm + (((mf*16 + lm) * ROWB + kb) ^ xm));
        #pragma unroll
        for (int nf = 0; nf < 4; ++nf)
            b[nf] = *(const bf16x8*)(wb + nf*16*KPAD + ks*32);
        #pragma unroll
        for (int mf = 0; mf < 4; ++mf)
            #pragma unroll
            for (int nf = 0; nf < 4; ++nf)
                acc[mf][nf] = __builtin_amdgcn_mfma_f32_16x16x32_bf16(a[mf], b[nf], acc[mf][nf], 0, 0, 0);
    }

    __syncthreads();   // all waves done READING act before anyone overwrites

    #pragma unroll
    for (int nf = 0; nf < 4; ++nf) {
        float bv = bias[n0 + nf*16 + lm];
        #pragma unroll
        for (int mf = 0; mf < 4; ++mf) {
            #pragma unroll
            for (int j = 0; j < 4; ++j) {
                int row = mf*16 + lk*4 + j;            // C layout: col=lane&15, row=(lane>>4)*4+j
                int col = n0 + nf*16 + lm;
                float v = acc[mf][nf][j] + bv;
                unsigned short h = f2bf(__sinf(v));
                int off = row * ROWB + col * 2;
                *(unsigned short*)(sm + (off ^ ((row & 7) << 4))) = h;
            }
        }
    }
    __syncthreads();   // writes visible before next layer reads
}

__global__ __launch_bounds__(512) void siren_fused(
    const float* __restrict__ coords, const float* __restrict__ table,
    const float* __restrict__ b1, const float* __restrict__ b2,
    const float* __restrict__ bs1, const float* __restrict__ bs2,
    const float* __restrict__ bo,
    const unsigned short* __restrict__ Wp,
    float* __restrict__ outp,
    ResArr res)
{
    extern __shared__ char sm[];
    const int tid = threadIdx.x;
    const int pbase = blockIdx.x * MBLK;

    // ---------------- hash encoding -> act cols 512..543 ----------------
    {
        int p  = tid & 63;
        int lg = tid >> 6;                 // 0..7; handles level lg and lg+8 (if <10)
        float cx = coords[(pbase + p) * 2 + 0];
        float cy = coords[(pbase + p) * 2 + 1];
        int xm = (p & 7) << 4;
        int rowbase = p * ROWB;
        #pragma unroll
        for (int li = 0; li < 2; ++li) {
            int l = lg + 8 * li;
            if (l < 10) {
                float R  = (float)res.r[l];
                float fx = cx * R, fy = cy * R;
                float x0 = floorf(fx), y0 = floorf(fy);
                float wx = fx - x0,  wy = fy - y0;
                unsigned xi = (unsigned)x0, yi = (unsigned)y0;
                unsigned yp  = yi * 2654435761u;
                unsigned yp1 = (yi + 1u) * 2654435761u;
                unsigned h00 = (xi        ^ yp ) & 4095u;
                unsigned h10 = ((xi + 1u) ^ yp ) & 4095u;
                unsigned h01 = (xi        ^ yp1) & 4095u;
                unsigned h11 = ((xi + 1u) ^ yp1) & 4095u;
                const float2* tl = (const float2*)(table + l * 8192);
                float2 f00 = tl[h00], f10 = tl[h10], f01 = tl[h01], f11 = tl[h11];
                float a0 = f00.x + (f10.x - f00.x) * wx;
                float a1 = f01.x + (f11.x - f01.x) * wx;
                float g0 = a0 + (a1 - a0) * wy;
                float c0 = f00.y + (f10.y - f00.y) * wx;
                float c1 = f01.y + (f11.y - f01.y) * wx;
                float g1 = c0 + (c1 - c0) * wy;
                unsigned pk = (unsigned)f2bf(g0) | ((unsigned)f2bf(g1) << 16);
                int off = rowbase + (512 + 2 * l) * 2;
                *(unsigned*)(sm + (off ^ xm)) = pk;
            }
        }
        if (lg == 2) {   // coords -> cols 532,533
            unsigned pk = (unsigned)f2bf(cx) | ((unsigned)f2bf(cy) << 16);
            int off = rowbase + 532 * 2;
            *(unsigned*)(sm + (off ^ xm)) = pk;
        }
        if (lg == 3) {   // zero pad cols 534..543
            #pragma unroll
            for (int c = 534; c < 544; c += 2) {
                int off = rowbase + c * 2;
                *(unsigned*)(sm + (off ^ xm)) = 0u;
            }
        }
    }
    __syncthreads();

    const int wid  = tid >> 6;
    const int lane = tid & 63;

    mlp_layer<1,  32 >(sm, Wp + OFF_W1,  b1,  1024, wid, lane);   // h0(22,pad32) -> 512
    mlp_layer<16, 512>(sm, Wp + OFF_W2,  b2,  0,    wid, lane);   // 512 -> 512
    mlp_layer<17, 544>(sm, Wp + OFF_WS1, bs1, 0,    wid, lane);   // [a2|h0] 544 -> 512
    mlp_layer<16, 512>(sm, Wp + OFF_WS2, bs2, 0,    wid, lane);   // 512 -> 512

    // ---------------- output layer: 512 -> 2, sin, f32 out ----------------
    {
        int p = tid >> 3, g = tid & 7;
        const unsigned short* wo0 = Wp + OFF_WO + g * 64;
        const unsigned short* wo1 = wo0 + 512;
        int xm = (p & 7) << 4;
        float s0 = 0.f, s1 = 0.f;
        #pragma unroll
        for (int kk = 0; kk < 8; ++kk) {
            int off = p * ROWB + (g * 64 + kk * 8) * 2;
            bf16x8 av  = *(const bf16x8*)(sm + (off ^ xm));
            bf16x8 w0  = *(const bf16x8*)(wo0 + kk * 8);
            bf16x8 w1v = *(const bf16x8*)(wo1 + kk * 8);
            #pragma unroll
            for (int j = 0; j < 8; ++j) {
                float a = bf2f((unsigned short)av[j]);
                s0 += a * bf2f((unsigned short)w0[j]);
                s1 += a * bf2f((unsigned short)w1v[j]);
            }
        }
        #pragma unroll
        for (int m = 1; m < 8; m <<= 1) {
            s0 += __shfl_xor(s0, m, 64);
            s1 += __shfl_xor(s1, m, 64);
        }
        if (g == 0) {
            float2 o;
            o.x = __sinf(s0 + bo[0]);
            o.y = __sinf(s1 + bo[1]);
            ((float2*)outp)[pbase + p] = o;
        }
    }
}

extern "C" void kernel_launch(void* const* d_in, const int* in_sizes, int n_in,
                              void* d_out, int out_size, void* d_ws, size_t ws_size,
                              hipStream_t stream)
{
    const float* coords = (const float*)d_in[0];
    const float* table  = (const float*)d_in[1];
    const float* w1  = (const float*)d_in[2];
    const float* b1  = (const float*)d_in[3];
    const float* w2  = (const float*)d_in[4];
    const float* b2  = (const float*)d_in[5];
    const float* ws1 = (const float*)d_in[6];
    const float* bs1 = (const float*)d_in[7];
    const float* ws2 = (const float*)d_in[8];
    const float* bs2 = (const float*)d_in[9];
    const float* wo  = (const float*)d_in[10];
    const float* bo  = (const float*)d_in[11];

    unsigned short* Wp = (unsigned short*)d_ws;
    float* outp = (float*)d_out;

    // RES computed with the exact double-precision op sequence of the reference
    ResArr res;
    double bb = exp((log(320.0) - log(16.0)) / 9.0);
    for (int l = 0; l < 10; ++l) res.r[l] = (int)floor(16.0 * pow(bb, (double)l));

    (void)hipFuncSetAttribute((const void*)siren_fused,
                              hipFuncAttributeMaxDynamicSharedMemorySize, LDSB);

    int N = in_sizes[0] / 2;      // 262144

    pack_weights<<<(NPACK + 255) / 256, 256, 0, stream>>>(w1, w2, ws1, ws2, wo, Wp);
    siren_fused<<<N / MBLK, 512, LDSB, stream>>>(coords, table, b1, b2, bs1, bs2, bo,
                                                 Wp, outp, res);
}

// Round 3
// 790.105 us; speedup vs baseline: 1.0213x; 1.0213x over previous
//
#include <hip/hip_runtime.h>
#include <hip/hip_bf16.h>
#include <math.h>

#define MBLK    64
#define BUF_SZ  65536                 // 64 rows x 512 cols x 2B
#define H0_OFF  (2*BUF_SZ)            // 131072
#define LDSB    (H0_OFF + 64*64)      // 135168 (h0: 64 rows x 32 cols x 2B)

// packed bf16 weight offsets (ushort elements) inside d_ws
#define OFF_W1  0
#define OFF_W2  16384                    // 512*32
#define OFF_WS1 (16384+262144)           // 278528
#define OFF_WS2 (278528+278528)          // 557056
#define OFF_WO  (557056+262144)          // 819200
#define NPACK   (819200+1024)            // 820224

typedef __attribute__((ext_vector_type(8))) short bf16x8;
typedef __attribute__((ext_vector_type(4))) float f32x4;

struct ResArr { int r[10]; };

__device__ __forceinline__ unsigned short f2bf(float f) {
    unsigned u = __float_as_uint(f);
    u += 0x7FFFu + ((u >> 16) & 1u);       // RNE
    return (unsigned short)(u >> 16);
}
__device__ __forceinline__ float bf2f(unsigned short h) {
    return __uint_as_float(((unsigned)h) << 16);
}
__device__ __forceinline__ unsigned short sin_bf16(float x) {
    float s = __sinf(x);
    unsigned pk;
    asm("v_cvt_pk_bf16_f32 %0, %1, %2" : "=v"(pk) : "v"(s), "v"(s));
    return (unsigned short)pk;
}

// swizzled addresses: activation buffers (1024B rows) and h0 block (64B rows)
__device__ __forceinline__ int aaddr(int buf, int row, int kb) {
    return buf * BUF_SZ + (((row << 10) + kb) ^ ((row & 7) << 4));
}
__device__ __forceinline__ int haddr(int row, int kb) {
    return H0_OFF + (((row << 6) + kb) ^ ((row & 7) << 4));
}

__global__ void pack_weights(const float* __restrict__ w1, const float* __restrict__ w2,
                             const float* __restrict__ ws1, const float* __restrict__ ws2,
                             const float* __restrict__ wo, unsigned short* __restrict__ out)
{
    int i = blockIdx.x * 256 + threadIdx.x;
    if (i >= NPACK) return;
    float v;
    if (i < OFF_W2)       { int n = i >> 5,  k = i & 31;  v = (k < 22)  ? w1[n*22 + k]  : 0.f; }
    else if (i < OFF_WS1) { int j = i - OFF_W2;  int n = j >> 9, k = j & 511; v = w2[n*512 + k]; }
    else if (i < OFF_WS2) { int j = i - OFF_WS1; int n = j / 544, k = j - n*544; v = (k < 534) ? ws1[n*534 + k] : 0.f; }
    else if (i < OFF_WO)  { int j = i - OFF_WS2; int n = j >> 9, k = j & 511; v = ws2[n*512 + k]; }
    else                  { int j = i - OFF_WO;  v = wo[j]; }
    out[i] = f2bf(v);
}

// one MLP layer: act[64 x K] (srcBuf / h0 tail) @ W^T -> sin -> dstBuf. ONE barrier.
template<int KMAIN, bool TAIL, int KPAD>
__device__ __forceinline__ void mlp_layer(char* sm, int srcBuf, int dstBuf,
                                          const unsigned short* __restrict__ Wp,
                                          const float* __restrict__ bias,
                                          int wid, int lane)
{
    const int n0 = wid * 64;
    const int lm = lane & 15;
    const int lk = lane >> 4;               // 0..3
    const int xm = (lm & 7) << 4;

    float bv[4];
    #pragma unroll
    for (int nf = 0; nf < 4; ++nf) bv[nf] = bias[n0 + nf*16 + lm];

    f32x4 acc[4][4];
    #pragma unroll
    for (int i = 0; i < 4; ++i)
        #pragma unroll
        for (int j = 0; j < 4; ++j) { f32x4 z = {0.f,0.f,0.f,0.f}; acc[i][j] = z; }

    const unsigned short* wb = Wp + (unsigned)(n0 + lm) * KPAD + lk * 8;

    #pragma unroll 4
    for (int ks = 0; ks < KMAIN; ++ks) {
        const int kb = ks * 64 + lk * 16;
        bf16x8 a[4], b[4];
        #pragma unroll
        for (int mf = 0; mf < 4; ++mf)
            a[mf] = *(const bf16x8*)(sm + srcBuf*BUF_SZ + ((((mf*16 + lm) << 10) + kb) ^ xm));
        #pragma unroll
        for (int nf = 0; nf < 4; ++nf)
            b[nf] = *(const bf16x8*)(wb + nf*16*KPAD + ks*32);
        #pragma unroll
        for (int mf = 0; mf < 4; ++mf)
            #pragma unroll
            for (int nf = 0; nf < 4; ++nf)
                acc[mf][nf] = __builtin_amdgcn_mfma_f32_16x16x32_bf16(a[mf], b[nf], acc[mf][nf], 0, 0, 0);
    }
    if (TAIL) {   // K-tail of 32 read from the h0 block
        const int kb = lk * 16;
        bf16x8 a[4], b[4];
        #pragma unroll
        for (int mf = 0; mf < 4; ++mf)
            a[mf] = *(const bf16x8*)(sm + haddr(mf*16 + lm, kb));
        #pragma unroll
        for (int nf = 0; nf < 4; ++nf)
            b[nf] = *(const bf16x8*)(wb + nf*16*KPAD + KMAIN*32);
        #pragma unroll
        for (int mf = 0; mf < 4; ++mf)
            #pragma unroll
            for (int nf = 0; nf < 4; ++nf)
                acc[mf][nf] = __builtin_amdgcn_mfma_f32_16x16x32_bf16(a[mf], b[nf], acc[mf][nf], 0, 0, 0);
    }

    // epilogue: bias + sin -> bf16 -> dstBuf (no barrier needed before: dst != src)
    #pragma unroll
    for (int nf = 0; nf < 4; ++nf) {
        const int colb = (n0 + nf*16 + lm) * 2;
        #pragma unroll
        for (int mf = 0; mf < 4; ++mf) {
            #pragma unroll
            for (int j = 0; j < 4; ++j) {
                int row = mf*16 + lk*4 + j;        // C layout: col=lane&15, row=(lane>>4)*4+j
                unsigned short h = sin_bf16(acc[mf][nf][j] + bv[nf]);
                *(unsigned short*)(sm + dstBuf*BUF_SZ + (((row << 10) + colb) ^ ((row & 7) << 4))) = h;
            }
        }
    }
    __syncthreads();   // dst complete; src free for reuse
}

__global__ __launch_bounds__(512) void siren_fused(
    const float* __restrict__ coords, const float* __restrict__ table,
    const float* __restrict__ b1, const float* __restrict__ b2,
    const float* __restrict__ bs1, const float* __restrict__ bs2,
    const float* __restrict__ bo,
    const unsigned short* __restrict__ Wp,
    float* __restrict__ outp,
    ResArr res)
{
    extern __shared__ char sm[];
    const int tid = threadIdx.x;
    const int pbase = blockIdx.x * MBLK;

    // ---------------- hash encoding -> h0 block (cols: 2l,2l+1 feats; 20,21 coords; 22..31 zero)
    {
        int p  = tid & 63;
        int lg = tid >> 6;                 // 0..7; handles level lg and lg+8
        float cx = coords[(pbase + p) * 2 + 0];
        float cy = coords[(pbase + p) * 2 + 1];
        #pragma unroll
        for (int li = 0; li < 2; ++li) {
            int l = lg + 8 * li;
            if (l < 10) {
                float R  = (float)res.r[l];
                float fx = cx * R, fy = cy * R;
                float x0 = floorf(fx), y0 = floorf(fy);
                float wx = fx - x0,  wy = fy - y0;
                unsigned xi = (unsigned)x0, yi = (unsigned)y0;
                unsigned yp  = yi * 2654435761u;
                unsigned yp1 = (yi + 1u) * 2654435761u;
                unsigned h00 = (xi        ^ yp ) & 4095u;
                unsigned h10 = ((xi + 1u) ^ yp ) & 4095u;
                unsigned h01 = (xi        ^ yp1) & 4095u;
                unsigned h11 = ((xi + 1u) ^ yp1) & 4095u;
                const float2* tl = (const float2*)(table + l * 8192);
                float2 f00 = tl[h00], f10 = tl[h10], f01 = tl[h01], f11 = tl[h11];
                float a0 = f00.x + (f10.x - f00.x) * wx;
                float a1 = f01.x + (f11.x - f01.x) * wx;
                float g0 = a0 + (a1 - a0) * wy;
                float c0 = f00.y + (f10.y - f00.y) * wx;
                float c1 = f01.y + (f11.y - f01.y) * wx;
                float g1 = c0 + (c1 - c0) * wy;
                unsigned pk = (unsigned)f2bf(g0) | ((unsigned)f2bf(g1) << 16);
                *(unsigned*)(sm + haddr(p, 4*l)) = pk;
            }
        }
        if (lg == 2) {   // coords -> cols 20,21 (byte 40)
            unsigned pk = (unsigned)f2bf(cx) | ((unsigned)f2bf(cy) << 16);
            *(unsigned*)(sm + haddr(p, 40)) = pk;
        }
        if (lg == 3) {   // zero pad cols 22..31 (bytes 44..63)
            #pragma unroll
            for (int bb = 44; bb < 64; bb += 4)
                *(unsigned*)(sm + haddr(p, bb)) = 0u;
        }
    }
    __syncthreads();

    const int wid  = tid >> 6;
    const int lane = tid & 63;

    mlp_layer<0,  true,  32 >(sm, 0, 0, Wp + OFF_W1,  b1,  wid, lane);  // h0(22p32) -> buf0
    mlp_layer<16, false, 512>(sm, 0, 1, Wp + OFF_W2,  b2,  wid, lane);  // buf0 -> buf1
    mlp_layer<16, true,  544>(sm, 1, 0, Wp + OFF_WS1, bs1, wid, lane);  // [buf1|h0] -> buf0
    mlp_layer<16, false, 512>(sm, 0, 1, Wp + OFF_WS2, bs2, wid, lane);  // buf0 -> buf1

    // ---------------- output layer: 512 -> 2, sin, f32 out ----------------
    {
        int p = tid >> 3, g = tid & 7;
        const unsigned short* wo0 = Wp + OFF_WO + g * 64;
        const unsigned short* wo1 = wo0 + 512;
        int xm = (p & 7) << 4;
        float s0 = 0.f, s1 = 0.f;
        #pragma unroll
        for (int kk = 0; kk < 8; ++kk) {
            int off = ((p << 10) + g*128 + kk*16) ^ xm;
            bf16x8 av  = *(const bf16x8*)(sm + BUF_SZ + off);
            bf16x8 w0  = *(const bf16x8*)(wo0 + kk * 8);
            bf16x8 w1v = *(const bf16x8*)(wo1 + kk * 8);
            #pragma unroll
            for (int j = 0; j < 8; ++j) {
                float a = bf2f((unsigned short)av[j]);
                s0 += a * bf2f((unsigned short)w0[j]);
                s1 += a * bf2f((unsigned short)w1v[j]);
            }
        }
        #pragma unroll
        for (int m = 1; m < 8; m <<= 1) {
            s0 += __shfl_xor(s0, m, 64);
            s1 += __shfl_xor(s1, m, 64);
        }
        if (g == 0) {
            float2 o;
            o.x = __sinf(s0 + bo[0]);
            o.y = __sinf(s1 + bo[1]);
            ((float2*)outp)[pbase + p] = o;
        }
    }
}

extern "C" void kernel_launch(void* const* d_in, const int* in_sizes, int n_in,
                              void* d_out, int out_size, void* d_ws, size_t ws_size,
                              hipStream_t stream)
{
    const float* coords = (const float*)d_in[0];
    const float* table  = (const float*)d_in[1];
    const float* w1  = (const float*)d_in[2];
    const float* b1  = (const float*)d_in[3];
    const float* w2  = (const float*)d_in[4];
    const float* b2  = (const float*)d_in[5];
    const float* ws1 = (const float*)d_in[6];
    const float* bs1 = (const float*)d_in[7];
    const float* ws2 = (const float*)d_in[8];
    const float* bs2 = (const float*)d_in[9];
    const float* wo  = (const float*)d_in[10];
    const float* bo  = (const float*)d_in[11];

    unsigned short* Wp = (unsigned short*)d_ws;
    float* outp = (float*)d_out;

    // RES computed with the exact double-precision op sequence of the reference
    ResArr res;
    double bb = exp((log(320.0) - log(16.0)) / 9.0);
    for (int l = 0; l < 10; ++l) res.r[l] = (int)floor(16.0 * pow(bb, (double)l));

    (void)hipFuncSetAttribute((const void*)siren_fused,
                              hipFuncAttributeMaxDynamicSharedMemorySize, LDSB);

    int N = in_sizes[0] / 2;      // 262144

    pack_weights<<<(NPACK + 255) / 256, 256, 0, stream>>>(w1, w2, ws1, ws2, wo, Wp);
    siren_fused<<<N / MBLK, 512, LDSB, stream>>>(coords, table, b1, b2, bs1, bs2, bo,
                                                 Wp, outp, res);
}